// Round 1
// baseline (58452.869 us; speedup 1.0000x reference)
//
#include <hip/hip_runtime.h>
#include <hip/hip_cooperative_groups.h>
#include <math.h>

namespace cg = cooperative_groups;

#define Bb 32
#define Ss 256
#define Vv 10000
#define Ee 512
#define Hh 1024
#define Ll 3
#define FH 4096

typedef short short8 __attribute__((ext_vector_type(8)));
typedef float floatx4 __attribute__((ext_vector_type(4)));

__device__ __forceinline__ float sigf(float x) { return 1.0f / (1.0f + expf(-x)); }

// split fp32 -> bf16 hi/lo (RNE). packed u32: low16 = hi, high16 = lo
__device__ __forceinline__ unsigned pack_hl(float x) {
    unsigned u = __float_as_uint(x);
    unsigned r = u + 0x7fff + ((u >> 16) & 1);
    unsigned hi = r >> 16;
    float hf = __uint_as_float(hi << 16);
    float l = x - hf;
    unsigned ul = __float_as_uint(l);
    unsigned rl = ul + 0x7fff + ((ul >> 16) & 1);
    return hi | ((rl >> 16) << 16);
}
__device__ __forceinline__ void split_hl(float x, unsigned short& h, unsigned short& l) {
    unsigned p = pack_hl(x);
    h = (unsigned short)(p & 0xffff);
    l = (unsigned short)(p >> 16);
}

// ---------------------------------------------------------------------------
// pack fp32 weights -> packed bf16 hi/lo u32 (vectorized float4)
// ---------------------------------------------------------------------------
__global__ __launch_bounds__(256) void pack_split(
    const float* __restrict__ src, unsigned* __restrict__ dst, int n4)
{
    int i = blockIdx.x * 256 + threadIdx.x;
    if (i < n4) {
        float4 v = ((const float4*)src)[i];
        uint4 o;
        o.x = pack_hl(v.x); o.y = pack_hl(v.y); o.z = pack_hl(v.z); o.w = pack_hl(v.w);
        ((uint4*)dst)[i] = o;
    }
}

// ---------------------------------------------------------------------------
// K1: layer-norm over seq dim of fix_pred, then per-layer mask/gate scalars.
// mask/gate layout: [L][S][B] -> idx l*8192 + s*32 + b
// ---------------------------------------------------------------------------
__global__ __launch_bounds__(256) void maskgate_kernel(
    const float* __restrict__ fp_in, float* __restrict__ mask, float* __restrict__ gate)
{
    __shared__ float red[256];
    int b = blockIdx.x, t = threadIdx.x;
    float v = fp_in[b * Ss + t];
    red[t] = v;
    __syncthreads();
    for (int o = 128; o > 0; o >>= 1) { if (t < o) red[t] += red[t + o]; __syncthreads(); }
    float mu = red[0] * (1.0f / Ss);
    __syncthreads();
    float d = v - mu;
    red[t] = d * d;
    __syncthreads();
    for (int o = 128; o > 0; o >>= 1) { if (t < o) red[t] += red[t + o]; __syncthreads(); }
    float var = red[0] * (1.0f / Ss);
    float fp = d * (1.0f / sqrtf(var + 1e-5f));
    fp = (fp + 1.96f) / 3.92f * 12.0f;
    float alpha0 = (11.0f - fp) * 0.25f;   // RESCALE = 12//3 = 4
    for (int l = 0; l < Ll; ++l) {
        float a = alpha0 - (float)l;
        float m = sigf(a);
        float g = sigf(a + 1.0f) - m;
        mask[l * (Ss * Bb) + t * Bb + b] = m;
        gate[l * (Ss * Bb) + t * Bb + b] = g;
    }
}

// ---------------------------------------------------------------------------
// fp32 NT GEMM (kept for the two small GEMMs):
// MODE 0: A gathered from emb via src; C = input_x + b_lin
// MODE 3: A plain; C = tanh(acc + bias)   (FC1 -> hid)
// ---------------------------------------------------------------------------
template <int MODE>
__global__ __launch_bounds__(256) void gemm_nt(
    const float* __restrict__ Amat, const float* __restrict__ Bmat,
    const float* __restrict__ bias1,
    float* __restrict__ Cmat, int M, int N, int K,
    const int* __restrict__ srcIdx, const float* __restrict__ embTab)
{
    __shared__ float As[16][68];
    __shared__ float Bs[16][68];
    int t = threadIdx.x;
    int tx = t & 15, ty = t >> 4;
    int n0 = blockIdx.x * 64, m0 = blockIdx.y * 64;
    int li = t >> 2;
    int lk = (t & 3) * 4;
    float acc[4][4];
#pragma unroll
    for (int y = 0; y < 4; ++y)
#pragma unroll
        for (int x = 0; x < 4; ++x) acc[y][x] = 0.0f;

    for (int k0 = 0; k0 < K; k0 += 16) {
        float a0, a1, a2, a3;
        {
            int r = m0 + li;
            if (MODE == 0) {
                int idx = srcIdx[(r & 31) * Ss + (r >> 5)];
                float4 v = *(const float4*)(embTab + (size_t)idx * K + (k0 + lk));
                a0 = v.x; a1 = v.y; a2 = v.z; a3 = v.w;
            } else {
                float4 v = *(const float4*)(Amat + (size_t)r * K + (k0 + lk));
                a0 = v.x; a1 = v.y; a2 = v.z; a3 = v.w;
            }
        }
        As[lk + 0][li] = a0; As[lk + 1][li] = a1; As[lk + 2][li] = a2; As[lk + 3][li] = a3;
        {
            int n = n0 + li;
            float b0 = 0.f, b1 = 0.f, b2 = 0.f, b3 = 0.f;
            if (n < N) {
                float4 v = *(const float4*)(Bmat + (size_t)n * K + (k0 + lk));
                b0 = v.x; b1 = v.y; b2 = v.z; b3 = v.w;
            }
            Bs[lk + 0][li] = b0; Bs[lk + 1][li] = b1; Bs[lk + 2][li] = b2; Bs[lk + 3][li] = b3;
        }
        __syncthreads();
#pragma unroll
        for (int kk = 0; kk < 16; ++kk) {
            float4 av = *(const float4*)&As[kk][ty * 4];
            float4 bv = *(const float4*)&Bs[kk][tx * 4];
            float avc[4] = {av.x, av.y, av.z, av.w};
            float bvc[4] = {bv.x, bv.y, bv.z, bv.w};
#pragma unroll
            for (int y = 0; y < 4; ++y)
#pragma unroll
                for (int x = 0; x < 4; ++x)
                    acc[y][x] = fmaf(avc[y], bvc[x], acc[y][x]);
        }
        __syncthreads();
    }
#pragma unroll
    for (int y = 0; y < 4; ++y) {
        int r = m0 + ty * 4 + y;
#pragma unroll
        for (int x = 0; x < 4; ++x) {
            int n = n0 + tx * 4 + x;
            if (n < N) {
                float vv = acc[y][x];
                if (MODE == 0) Cmat[(size_t)r * N + n] = vv + bias1[n];
                else           Cmat[(size_t)r * N + n] = tanhf(vv + bias1[n]);
            }
        }
    }
}

// ---------------------------------------------------------------------------
// MFMA split-bf16 NT GEMM: C[M,N] = A[M,K] * B[N,K]^T in ~fp32 precision.
// ---------------------------------------------------------------------------
template <int MODE>
__global__ __launch_bounds__(256) void gemm_mfma(
    const float* __restrict__ Amat, const unsigned* __restrict__ Bp,
    const float* __restrict__ bias1, const float* __restrict__ bias2,
    float* __restrict__ Cmat, int M, int N, int K,
    const float* __restrict__ xb, const float* __restrict__ ixb,
    const float* __restrict__ gateArr, int rowOff,
    float* __restrict__ outDst)
{
    __shared__ unsigned short As_h[128][40];
    __shared__ unsigned short As_l[128][40];
    __shared__ unsigned short Bs_h[128][40];
    __shared__ unsigned short Bs_l[128][40];

    const int t = threadIdx.x;
    const int n0 = blockIdx.x * 128, m0 = blockIdx.y * 128;
    const int lane = t & 63, w = t >> 6;
    const int mb = (w & 1) * 64, nb = (w >> 1) * 64;
    const int row = lane & 15, grp8 = (lane >> 4) * 8;

    const int arow = t >> 1;
    const int kseg = (t & 1) * 16;

    float gblend = 0.0f;
    const float* aptr = nullptr;
    const float* xptr = nullptr;
    if (MODE == 1 || MODE == 2) {
        int rg = rowOff + m0 + arow;
        gblend = gateArr[rg];
        aptr = ixb + (size_t)rg * K;
        if (MODE == 2) xptr = xb + (size_t)rg * K;
    } else {
        aptr = Amat + (size_t)(m0 + arow) * K;
    }
    const int bn = n0 + arow;
    const unsigned* bptr = Bp + (size_t)(bn < N ? bn : 0) * K;
    const bool bvalid = (bn < N);

    floatx4 acc[4][4];
#pragma unroll
    for (int i = 0; i < 4; ++i)
#pragma unroll
        for (int j = 0; j < 4; ++j)
            acc[i][j] = (floatx4){0.f, 0.f, 0.f, 0.f};

    for (int k0 = 0; k0 < K; k0 += 32) {
        unsigned short hbuf[16], lbuf[16];
#pragma unroll
        for (int u = 0; u < 4; ++u) {
            float4 vi = *(const float4*)(aptr + k0 + kseg + u * 4);
            float vals[4] = {vi.x, vi.y, vi.z, vi.w};
            if (MODE == 1) {
#pragma unroll
                for (int c = 0; c < 4; ++c) vals[c] *= gblend;
            } else if (MODE == 2) {
                float4 vx = *(const float4*)(xptr + k0 + kseg + u * 4);
                float xs[4] = {vx.x, vx.y, vx.z, vx.w};
#pragma unroll
                for (int c = 0; c < 4; ++c) vals[c] = xs[c] + (vals[c] - xs[c]) * gblend;
            }
#pragma unroll
            for (int c = 0; c < 4; ++c) split_hl(vals[c], hbuf[u * 4 + c], lbuf[u * 4 + c]);
        }
        {
            uint4 ph, pl;
            ph.x = hbuf[0] | ((unsigned)hbuf[1] << 16);
            ph.y = hbuf[2] | ((unsigned)hbuf[3] << 16);
            ph.z = hbuf[4] | ((unsigned)hbuf[5] << 16);
            ph.w = hbuf[6] | ((unsigned)hbuf[7] << 16);
            pl.x = lbuf[0] | ((unsigned)lbuf[1] << 16);
            pl.y = lbuf[2] | ((unsigned)lbuf[3] << 16);
            pl.z = lbuf[4] | ((unsigned)lbuf[5] << 16);
            pl.w = lbuf[6] | ((unsigned)lbuf[7] << 16);
            *(uint4*)&As_h[arow][kseg] = ph;
            *(uint4*)&As_l[arow][kseg] = pl;
            uint4 ph2, pl2;
            ph2.x = hbuf[8] | ((unsigned)hbuf[9] << 16);
            ph2.y = hbuf[10] | ((unsigned)hbuf[11] << 16);
            ph2.z = hbuf[12] | ((unsigned)hbuf[13] << 16);
            ph2.w = hbuf[14] | ((unsigned)hbuf[15] << 16);
            pl2.x = lbuf[8] | ((unsigned)lbuf[9] << 16);
            pl2.y = lbuf[10] | ((unsigned)lbuf[11] << 16);
            pl2.z = lbuf[12] | ((unsigned)lbuf[13] << 16);
            pl2.w = lbuf[14] | ((unsigned)lbuf[15] << 16);
            *(uint4*)&As_h[arow][kseg + 8] = ph2;
            *(uint4*)&As_l[arow][kseg + 8] = pl2;
        }
        {
            unsigned short bh[16], bl[16];
            if (bvalid) {
#pragma unroll
                for (int u = 0; u < 4; ++u) {
                    uint4 q = *(const uint4*)(bptr + k0 + kseg + u * 4);
                    unsigned qs[4] = {q.x, q.y, q.z, q.w};
#pragma unroll
                    for (int c = 0; c < 4; ++c) {
                        bh[u * 4 + c] = (unsigned short)(qs[c] & 0xffff);
                        bl[u * 4 + c] = (unsigned short)(qs[c] >> 16);
                    }
                }
            } else {
#pragma unroll
                for (int c = 0; c < 16; ++c) { bh[c] = 0; bl[c] = 0; }
            }
            uint4 ph, pl;
            ph.x = bh[0] | ((unsigned)bh[1] << 16);
            ph.y = bh[2] | ((unsigned)bh[3] << 16);
            ph.z = bh[4] | ((unsigned)bh[5] << 16);
            ph.w = bh[6] | ((unsigned)bh[7] << 16);
            pl.x = bl[0] | ((unsigned)bl[1] << 16);
            pl.y = bl[2] | ((unsigned)bl[3] << 16);
            pl.z = bl[4] | ((unsigned)bl[5] << 16);
            pl.w = bl[6] | ((unsigned)bl[7] << 16);
            *(uint4*)&Bs_h[arow][kseg] = ph;
            *(uint4*)&Bs_l[arow][kseg] = pl;
            uint4 ph2, pl2;
            ph2.x = bh[8] | ((unsigned)bh[9] << 16);
            ph2.y = bh[10] | ((unsigned)bh[11] << 16);
            ph2.z = bh[12] | ((unsigned)bh[13] << 16);
            ph2.w = bh[14] | ((unsigned)bh[15] << 16);
            pl2.x = bl[8] | ((unsigned)bl[9] << 16);
            pl2.y = bl[10] | ((unsigned)bl[11] << 16);
            pl2.z = bl[12] | ((unsigned)bl[13] << 16);
            pl2.w = bl[14] | ((unsigned)bl[15] << 16);
            *(uint4*)&Bs_h[arow][kseg + 8] = ph2;
            *(uint4*)&Bs_l[arow][kseg + 8] = pl2;
        }
        __syncthreads();
        short8 ah[4], al[4], bh8[4], bl8[4];
#pragma unroll
        for (int i = 0; i < 4; ++i) {
            ah[i] = *(const short8*)&As_h[mb + i * 16 + row][grp8];
            al[i] = *(const short8*)&As_l[mb + i * 16 + row][grp8];
            bh8[i] = *(const short8*)&Bs_h[nb + i * 16 + row][grp8];
            bl8[i] = *(const short8*)&Bs_l[nb + i * 16 + row][grp8];
        }
#pragma unroll
        for (int i = 0; i < 4; ++i)
#pragma unroll
            for (int j = 0; j < 4; ++j) {
                acc[i][j] = __builtin_amdgcn_mfma_f32_16x16x32_bf16(ah[i], bh8[j], acc[i][j], 0, 0, 0);
                acc[i][j] = __builtin_amdgcn_mfma_f32_16x16x32_bf16(al[i], bh8[j], acc[i][j], 0, 0, 0);
                acc[i][j] = __builtin_amdgcn_mfma_f32_16x16x32_bf16(ah[i], bl8[j], acc[i][j], 0, 0, 0);
            }
        __syncthreads();
    }

    const int grp = lane >> 4;
#pragma unroll
    for (int i = 0; i < 4; ++i) {
        int mbase = m0 + mb + i * 16 + grp * 4;
#pragma unroll
        for (int j = 0; j < 4; ++j) {
            int n = n0 + nb + j * 16 + (lane & 15);
#pragma unroll
            for (int r = 0; r < 4; ++r) {
                float vv = acc[i][j][r];
                int mm = mbase + r;
                if (MODE == 4) {
                    if (n < N)
                        outDst[((size_t)(mm & 31) * Ss + (mm >> 5)) * Vv + n] = vv + bias1[n];
                } else {
                    Cmat[(size_t)mm * N + n] = vv + bias1[n] + bias2[n];
                }
            }
        }
    }
}

// ---------------------------------------------------------------------------
// Persistent cooperative LSTM: 64 time steps in ONE launch, grid.sync between
// steps. 256 blocks x 512 threads. Block owns 4 h-columns (j0..j0+3) -> 16
// rows of Wh (4 gates x 4 cols). Thread = (batch b, row-group rg of 8 rows,
// k-eighth kh): register-blocks 8 rows so each staged h float4 feeds 32 FMAs.
// Weights stream from global (L2-resident, 64KB/CU reused all 64 steps).
// h double-buffered in global (hb[2]); c + own h column live in registers.
// ---------------------------------------------------------------------------
__global__ __launch_bounds__(512) void lstm_chunk(
    const float* __restrict__ Gc,     // [64][32][4096] gate pre-activations
    const float* __restrict__ Wh,     // [4096][1024]
    const float* __restrict__ maskL,  // [256][32] this layer's mask
    float* __restrict__ hb,           // [2][32][1024]
    float* __restrict__ cb,           // [32][1024]
    float* __restrict__ xout,         // [256][32][1024] layer output base
    int s0)                           // global step of first step (ch*64, even)
{
    __shared__ float hs[32 * 132];      // staged h chunk  (16.9 KB)
    __shared__ float gbuf[8 * 16 * 32]; // k-eighth partials (16 KB)
    __shared__ float msk[64 * 32];      // this chunk's mask (8 KB)

    cg::grid_group grid = cg::this_grid();

    const int t  = threadIdx.x;
    const int j0 = blockIdx.x * 4;
    const int b  = t & 31;
    const int rg = (t >> 5) & 1;   // 2 row-groups of 8 rows
    const int kh = t >> 6;         // 8 k-eighths (16-float sub-blocks, strided)

    for (int i = t; i < 64 * 32; i += 512) msk[i] = maskL[s0 * 32 + i];

    const int b2 = t & 31, d2 = (t >> 5) & 3;
    float c_reg = 0.f, h_reg = 0.f;
    if (t < 128) {
        c_reg = cb[b2 * Hh + j0 + d2];
        h_reg = hb[b2 * Hh + j0 + d2];   // buffer 0 is current at chunk start
    }

    // 8 weight-row base pointers (local rows rg*8 .. rg*8+7), offset by kh*16
    const float* wr[8];
#pragma unroll
    for (int ri = 0; ri < 8; ++ri) {
        int lr = rg * 8 + ri;                         // lr = q*4 + d
        wr[ri] = Wh + (size_t)((lr >> 2) * Hh + j0 + (lr & 3)) * Hh + kh * 16;
    }

    for (int s = 0; s < 64; ++s) {
        const float* hprev = hb + ((s0 + s) & 1) * 32768;
        float* hnext       = hb + ((s0 + s + 1) & 1) * 32768;

        float ax[8], ay[8], az[8], aw[8];
#pragma unroll
        for (int ri = 0; ri < 8; ++ri) { ax[ri] = ay[ri] = az[ri] = aw[ri] = 0.f; }

        for (int kc = 0; kc < Hh; kc += 128) {
            // stage h chunk: 1024 float4, 2 per thread, coalesced
            {
                int i0 = t;
                int bl = i0 >> 5, k4 = i0 & 31;
                *(float4*)(hs + bl * 132 + k4 * 4) =
                    *(const float4*)(hprev + bl * Hh + kc + k4 * 4);
                int i1 = t + 512;
                bl = i1 >> 5; k4 = i1 & 31;
                *(float4*)(hs + bl * 132 + k4 * 4) =
                    *(const float4*)(hprev + bl * Hh + kc + k4 * 4);
            }
            __syncthreads();
            const float* hp = hs + b * 132 + kh * 16;
#pragma unroll
            for (int u = 0; u < 4; ++u) {
                float4 hv = *(const float4*)(hp + u * 4);
#pragma unroll
                for (int ri = 0; ri < 8; ++ri) {
                    float4 wv = *(const float4*)(wr[ri] + kc + u * 4);
                    ax[ri] = fmaf(wv.x, hv.x, ax[ri]);
                    ay[ri] = fmaf(wv.y, hv.y, ay[ri]);
                    az[ri] = fmaf(wv.z, hv.z, az[ri]);
                    aw[ri] = fmaf(wv.w, hv.w, aw[ri]);
                }
            }
            __syncthreads();
        }
        // deposit k-eighth partials (conflict-free: lanes differ in b)
#pragma unroll
        for (int ri = 0; ri < 8; ++ri) {
            int lr = rg * 8 + ri;
            gbuf[kh * 512 + lr * 32 + b] = (ax[ri] + ay[ri]) + (az[ri] + aw[ri]);
        }
        __syncthreads();
        if (t < 128) {
            float g4[4];
#pragma unroll
            for (int q = 0; q < 4; ++q) {
                int lr = q * 4 + d2;
                float sum = Gc[(size_t)s * (32 * FH) + b2 * FH + q * Hh + j0 + d2];
#pragma unroll
                for (int k2 = 0; k2 < 8; ++k2) sum += gbuf[k2 * 512 + lr * 32 + b2];
                g4[q] = sum;
            }
            float m  = msk[s * 32 + b2];
            float ct = sigf(g4[1]) * c_reg + sigf(g4[0]) * tanhf(g4[2]);
            float ht = sigf(g4[3]) * tanhf(ct);
            c_reg = ct + (c_reg - ct) * m;   // RHS c_reg is old c
            h_reg = ht + (h_reg - ht) * m;   // RHS h_reg is old h
            int j = j0 + d2;
            hnext[b2 * Hh + j] = h_reg;
            xout[(size_t)(s0 + s) * 32768 + b2 * Hh + j] = h_reg;
            __threadfence();                 // agent-scope: publish h across XCDs
        }
        grid.sync();
    }
    if (t < 128) cb[b2 * Hh + j0 + d2] = c_reg;
}

__global__ __launch_bounds__(256) void init_hc(
    const float* __restrict__ h0, const float* __restrict__ c0,
    float* __restrict__ hb0, float* __restrict__ cb)
{
    int i = blockIdx.x * 256 + threadIdx.x;
    hb0[i] = h0[i];
    cb[i] = c0[i];
}

// ---------------------------------------------------------------------------
extern "C" void kernel_launch(void* const* d_in, const int* in_sizes, int n_in,
                              void* d_out, int out_size, void* d_ws, size_t ws_size,
                              hipStream_t stream)
{
    const int*   src      = (const int*)  d_in[0];
    const float* fix_pred = (const float*)d_in[1];
    const float* emb      = (const float*)d_in[2];
    const float* W_lin    = (const float*)d_in[3];
    const float* b_lin    = (const float*)d_in[4];
    const float* W_ih     = (const float*)d_in[5];
    const float* W_hh     = (const float*)d_in[6];
    const float* b_ih     = (const float*)d_in[7];
    const float* b_hh     = (const float*)d_in[8];
    const float* fc_W1    = (const float*)d_in[9];
    const float* fc_b1    = (const float*)d_in[10];
    const float* fc_W2    = (const float*)d_in[11];
    const float* fc_b2    = (const float*)d_in[12];
    const float* h0       = (const float*)d_in[13];
    const float* c0       = (const float*)d_in[14];
    float* out = (float*)d_out;

    // workspace layout (floats)
    float* ws    = (float*)d_ws;
    float* ix    = ws;                    // 8388608  input_x [S*B][H]
    float* xbuf  = ix + 8388608;          // 8388608  x       [S*B][H]
    float* Gch   = xbuf + 8388608;        // 8388608  G chunk [2048][4096]
    float* hid   = Gch;                   // alias: hid [8192][512]
    unsigned* wpack = (unsigned*)(Gch + 8388608);  // 4194304 u32: Wi[l] packed
    float* hb    = (float*)(wpack + 4194304);      // 65536 (double-buffered h)
    float* cb    = hb + 65536;            // 32768
    float* mask  = cb + 32768;            // 24576
    float* gate  = mask + 24576;          // 24576

    maskgate_kernel<<<32, 256, 0, stream>>>(fix_pred, mask, gate);

    // input_x = emb[src] @ W_lin^T + b_lin : M=8192 N=1024 K=512 (fp32)
    gemm_nt<0><<<dim3(16, 128), 256, 0, stream>>>(
        nullptr, W_lin, b_lin, ix, 8192, 1024, 512, src, emb);

    for (int l = 0; l < Ll; ++l) {
        pack_split<<<4096, 256, 0, stream>>>(W_ih + (size_t)l * FH * Hh, wpack, 1048576);
        init_hc<<<128, 256, 0, stream>>>(h0 + (size_t)l * 32768, c0 + (size_t)l * 32768, hb, cb);
        const float* Wh = W_hh + (size_t)l * FH * Hh;
        const float* bi = b_ih + (size_t)l * FH;
        const float* bh = b_hh + (size_t)l * FH;
        for (int ch = 0; ch < 4; ++ch) {
            int rowOff = ch * 2048;
            // G = inp_seq @ Wi^T + bi + bh : M=2048 N=4096 K=1024 (MFMA split-3)
            if (l == 0) {
                gemm_mfma<1><<<dim3(32, 16), 256, 0, stream>>>(
                    nullptr, wpack, bi, bh, Gch, 2048, 4096, 1024,
                    nullptr, ix, gate + l * 8192, rowOff, nullptr);
            } else {
                gemm_mfma<2><<<dim3(32, 16), 256, 0, stream>>>(
                    nullptr, wpack, bi, bh, Gch, 2048, 4096, 1024,
                    xbuf, ix, gate + l * 8192, rowOff, nullptr);
            }
            // 64 LSTM steps in one cooperative launch
            {
                const float* GcArg   = Gch;
                const float* WhArg   = Wh;
                const float* maskArg = mask + l * 8192;
                float* hbArg = hb;
                float* cbArg = cb;
                float* xoArg = xbuf;
                int s0 = ch * 64;
                void* args[] = {
                    (void*)&GcArg, (void*)&WhArg, (void*)&maskArg,
                    (void*)&hbArg, (void*)&cbArg, (void*)&xoArg, (void*)&s0
                };
                hipLaunchCooperativeKernel((const void*)lstm_chunk,
                                           dim3(256), dim3(512), args, 0, stream);
            }
        }
    }

    // hid = tanh(x @ fc_W1^T + fc_b1) : M=8192 N=512 K=1024 (fp32)
    gemm_nt<3><<<dim3(8, 128), 256, 0, stream>>>(
        xbuf, fc_W1, fc_b1, hid, 8192, 512, 1024, nullptr, nullptr);

    // pack fc_W2 into the now-dead ix buffer; out = hid @ fc_W2^T + fc_b2
    unsigned* w2pack = (unsigned*)ix;
    pack_split<<<5000, 256, 0, stream>>>(fc_W2, w2pack, 1280000);
    gemm_mfma<4><<<dim3(79, 64), 256, 0, stream>>>(
        hid, w2pack, fc_b2, nullptr, nullptr, 8192, 10000, 512,
        nullptr, nullptr, nullptr, 0, out);
}

// Round 2
// 31754.492 us; speedup vs baseline: 1.8408x; 1.8408x over previous
//
#include <hip/hip_runtime.h>
#include <hip/hip_cooperative_groups.h>
#include <math.h>

#define Bb 32
#define Ss 256
#define Vv 10000
#define Ee 512
#define Hh 1024
#define Ll 3
#define FH 4096

typedef short short8 __attribute__((ext_vector_type(8)));
typedef float floatx4 __attribute__((ext_vector_type(4)));

__device__ __forceinline__ float sigf(float x) { return 1.0f / (1.0f + expf(-x)); }

// split fp32 -> bf16 hi/lo (RNE). packed u32: low16 = hi, high16 = lo
__device__ __forceinline__ unsigned pack_hl(float x) {
    unsigned u = __float_as_uint(x);
    unsigned r = u + 0x7fff + ((u >> 16) & 1);
    unsigned hi = r >> 16;
    float hf = __uint_as_float(hi << 16);
    float l = x - hf;
    unsigned ul = __float_as_uint(l);
    unsigned rl = ul + 0x7fff + ((ul >> 16) & 1);
    return hi | ((rl >> 16) << 16);
}
__device__ __forceinline__ void split_hl(float x, unsigned short& h, unsigned short& l) {
    unsigned p = pack_hl(x);
    h = (unsigned short)(p & 0xffff);
    l = (unsigned short)(p >> 16);
}

// ---------------------------------------------------------------------------
// pack fp32 weights -> packed bf16 hi/lo u32 (vectorized float4)
// ---------------------------------------------------------------------------
__global__ __launch_bounds__(256) void pack_split(
    const float* __restrict__ src, unsigned* __restrict__ dst, int n4)
{
    int i = blockIdx.x * 256 + threadIdx.x;
    if (i < n4) {
        float4 v = ((const float4*)src)[i];
        uint4 o;
        o.x = pack_hl(v.x); o.y = pack_hl(v.y); o.z = pack_hl(v.z); o.w = pack_hl(v.w);
        ((uint4*)dst)[i] = o;
    }
}

// ---------------------------------------------------------------------------
// K1: layer-norm over seq dim of fix_pred, then per-layer mask/gate scalars.
// mask/gate layout: [L][S][B] -> idx l*8192 + s*32 + b
// ---------------------------------------------------------------------------
__global__ __launch_bounds__(256) void maskgate_kernel(
    const float* __restrict__ fp_in, float* __restrict__ mask, float* __restrict__ gate)
{
    __shared__ float red[256];
    int b = blockIdx.x, t = threadIdx.x;
    float v = fp_in[b * Ss + t];
    red[t] = v;
    __syncthreads();
    for (int o = 128; o > 0; o >>= 1) { if (t < o) red[t] += red[t + o]; __syncthreads(); }
    float mu = red[0] * (1.0f / Ss);
    __syncthreads();
    float d = v - mu;
    red[t] = d * d;
    __syncthreads();
    for (int o = 128; o > 0; o >>= 1) { if (t < o) red[t] += red[t + o]; __syncthreads(); }
    float var = red[0] * (1.0f / Ss);
    float fp = d * (1.0f / sqrtf(var + 1e-5f));
    fp = (fp + 1.96f) / 3.92f * 12.0f;
    float alpha0 = (11.0f - fp) * 0.25f;   // RESCALE = 12//3 = 4
    for (int l = 0; l < Ll; ++l) {
        float a = alpha0 - (float)l;
        float m = sigf(a);
        float g = sigf(a + 1.0f) - m;
        mask[l * (Ss * Bb) + t * Bb + b] = m;
        gate[l * (Ss * Bb) + t * Bb + b] = g;
    }
}

// ---------------------------------------------------------------------------
// fp32 NT GEMM (kept for the two small GEMMs):
// MODE 0: A gathered from emb via src; C = input_x + b_lin
// MODE 3: A plain; C = tanh(acc + bias)   (FC1 -> hid)
// ---------------------------------------------------------------------------
template <int MODE>
__global__ __launch_bounds__(256) void gemm_nt(
    const float* __restrict__ Amat, const float* __restrict__ Bmat,
    const float* __restrict__ bias1,
    float* __restrict__ Cmat, int M, int N, int K,
    const int* __restrict__ srcIdx, const float* __restrict__ embTab)
{
    __shared__ float As[16][68];
    __shared__ float Bs[16][68];
    int t = threadIdx.x;
    int tx = t & 15, ty = t >> 4;
    int n0 = blockIdx.x * 64, m0 = blockIdx.y * 64;
    int li = t >> 2;
    int lk = (t & 3) * 4;
    float acc[4][4];
#pragma unroll
    for (int y = 0; y < 4; ++y)
#pragma unroll
        for (int x = 0; x < 4; ++x) acc[y][x] = 0.0f;

    for (int k0 = 0; k0 < K; k0 += 16) {
        float a0, a1, a2, a3;
        {
            int r = m0 + li;
            if (MODE == 0) {
                int idx = srcIdx[(r & 31) * Ss + (r >> 5)];
                float4 v = *(const float4*)(embTab + (size_t)idx * K + (k0 + lk));
                a0 = v.x; a1 = v.y; a2 = v.z; a3 = v.w;
            } else {
                float4 v = *(const float4*)(Amat + (size_t)r * K + (k0 + lk));
                a0 = v.x; a1 = v.y; a2 = v.z; a3 = v.w;
            }
        }
        As[lk + 0][li] = a0; As[lk + 1][li] = a1; As[lk + 2][li] = a2; As[lk + 3][li] = a3;
        {
            int n = n0 + li;
            float b0 = 0.f, b1 = 0.f, b2 = 0.f, b3 = 0.f;
            if (n < N) {
                float4 v = *(const float4*)(Bmat + (size_t)n * K + (k0 + lk));
                b0 = v.x; b1 = v.y; b2 = v.z; b3 = v.w;
            }
            Bs[lk + 0][li] = b0; Bs[lk + 1][li] = b1; Bs[lk + 2][li] = b2; Bs[lk + 3][li] = b3;
        }
        __syncthreads();
#pragma unroll
        for (int kk = 0; kk < 16; ++kk) {
            float4 av = *(const float4*)&As[kk][ty * 4];
            float4 bv = *(const float4*)&Bs[kk][tx * 4];
            float avc[4] = {av.x, av.y, av.z, av.w};
            float bvc[4] = {bv.x, bv.y, bv.z, bv.w};
#pragma unroll
            for (int y = 0; y < 4; ++y)
#pragma unroll
                for (int x = 0; x < 4; ++x)
                    acc[y][x] = fmaf(avc[y], bvc[x], acc[y][x]);
        }
        __syncthreads();
    }
#pragma unroll
    for (int y = 0; y < 4; ++y) {
        int r = m0 + ty * 4 + y;
#pragma unroll
        for (int x = 0; x < 4; ++x) {
            int n = n0 + tx * 4 + x;
            if (n < N) {
                float vv = acc[y][x];
                if (MODE == 0) Cmat[(size_t)r * N + n] = vv + bias1[n];
                else           Cmat[(size_t)r * N + n] = tanhf(vv + bias1[n]);
            }
        }
    }
}

// ---------------------------------------------------------------------------
// MFMA split-bf16 NT GEMM: C[M,N] = A[M,K] * B[N,K]^T in ~fp32 precision.
// ---------------------------------------------------------------------------
template <int MODE>
__global__ __launch_bounds__(256) void gemm_mfma(
    const float* __restrict__ Amat, const unsigned* __restrict__ Bp,
    const float* __restrict__ bias1, const float* __restrict__ bias2,
    float* __restrict__ Cmat, int M, int N, int K,
    const float* __restrict__ xb, const float* __restrict__ ixb,
    const float* __restrict__ gateArr, int rowOff,
    float* __restrict__ outDst)
{
    __shared__ unsigned short As_h[128][40];
    __shared__ unsigned short As_l[128][40];
    __shared__ unsigned short Bs_h[128][40];
    __shared__ unsigned short Bs_l[128][40];

    const int t = threadIdx.x;
    const int n0 = blockIdx.x * 128, m0 = blockIdx.y * 128;
    const int lane = t & 63, w = t >> 6;
    const int mb = (w & 1) * 64, nb = (w >> 1) * 64;
    const int row = lane & 15, grp8 = (lane >> 4) * 8;

    const int arow = t >> 1;
    const int kseg = (t & 1) * 16;

    float gblend = 0.0f;
    const float* aptr = nullptr;
    const float* xptr = nullptr;
    if (MODE == 1 || MODE == 2) {
        int rg = rowOff + m0 + arow;
        gblend = gateArr[rg];
        aptr = ixb + (size_t)rg * K;
        if (MODE == 2) xptr = xb + (size_t)rg * K;
    } else {
        aptr = Amat + (size_t)(m0 + arow) * K;
    }
    const int bn = n0 + arow;
    const unsigned* bptr = Bp + (size_t)(bn < N ? bn : 0) * K;
    const bool bvalid = (bn < N);

    floatx4 acc[4][4];
#pragma unroll
    for (int i = 0; i < 4; ++i)
#pragma unroll
        for (int j = 0; j < 4; ++j)
            acc[i][j] = (floatx4){0.f, 0.f, 0.f, 0.f};

    for (int k0 = 0; k0 < K; k0 += 32) {
        unsigned short hbuf[16], lbuf[16];
#pragma unroll
        for (int u = 0; u < 4; ++u) {
            float4 vi = *(const float4*)(aptr + k0 + kseg + u * 4);
            float vals[4] = {vi.x, vi.y, vi.z, vi.w};
            if (MODE == 1) {
#pragma unroll
                for (int c = 0; c < 4; ++c) vals[c] *= gblend;
            } else if (MODE == 2) {
                float4 vx = *(const float4*)(xptr + k0 + kseg + u * 4);
                float xs[4] = {vx.x, vx.y, vx.z, vx.w};
#pragma unroll
                for (int c = 0; c < 4; ++c) vals[c] = xs[c] + (vals[c] - xs[c]) * gblend;
            }
#pragma unroll
            for (int c = 0; c < 4; ++c) split_hl(vals[c], hbuf[u * 4 + c], lbuf[u * 4 + c]);
        }
        {
            uint4 ph, pl;
            ph.x = hbuf[0] | ((unsigned)hbuf[1] << 16);
            ph.y = hbuf[2] | ((unsigned)hbuf[3] << 16);
            ph.z = hbuf[4] | ((unsigned)hbuf[5] << 16);
            ph.w = hbuf[6] | ((unsigned)hbuf[7] << 16);
            pl.x = lbuf[0] | ((unsigned)lbuf[1] << 16);
            pl.y = lbuf[2] | ((unsigned)lbuf[3] << 16);
            pl.z = lbuf[4] | ((unsigned)lbuf[5] << 16);
            pl.w = lbuf[6] | ((unsigned)lbuf[7] << 16);
            *(uint4*)&As_h[arow][kseg] = ph;
            *(uint4*)&As_l[arow][kseg] = pl;
            uint4 ph2, pl2;
            ph2.x = hbuf[8] | ((unsigned)hbuf[9] << 16);
            ph2.y = hbuf[10] | ((unsigned)hbuf[11] << 16);
            ph2.z = hbuf[12] | ((unsigned)hbuf[13] << 16);
            ph2.w = hbuf[14] | ((unsigned)hbuf[15] << 16);
            pl2.x = lbuf[8] | ((unsigned)lbuf[9] << 16);
            pl2.y = lbuf[10] | ((unsigned)lbuf[11] << 16);
            pl2.z = lbuf[12] | ((unsigned)lbuf[13] << 16);
            pl2.w = lbuf[14] | ((unsigned)lbuf[15] << 16);
            *(uint4*)&As_h[arow][kseg + 8] = ph2;
            *(uint4*)&As_l[arow][kseg + 8] = pl2;
        }
        {
            unsigned short bh[16], bl[16];
            if (bvalid) {
#pragma unroll
                for (int u = 0; u < 4; ++u) {
                    uint4 q = *(const uint4*)(bptr + k0 + kseg + u * 4);
                    unsigned qs[4] = {q.x, q.y, q.z, q.w};
#pragma unroll
                    for (int c = 0; c < 4; ++c) {
                        bh[u * 4 + c] = (unsigned short)(qs[c] & 0xffff);
                        bl[u * 4 + c] = (unsigned short)(qs[c] >> 16);
                    }
                }
            } else {
#pragma unroll
                for (int c = 0; c < 16; ++c) { bh[c] = 0; bl[c] = 0; }
            }
            uint4 ph, pl;
            ph.x = bh[0] | ((unsigned)bh[1] << 16);
            ph.y = bh[2] | ((unsigned)bh[3] << 16);
            ph.z = bh[4] | ((unsigned)bh[5] << 16);
            ph.w = bh[6] | ((unsigned)bh[7] << 16);
            pl.x = bl[0] | ((unsigned)bl[1] << 16);
            pl.y = bl[2] | ((unsigned)bl[3] << 16);
            pl.z = bl[4] | ((unsigned)bl[5] << 16);
            pl.w = bl[6] | ((unsigned)bl[7] << 16);
            *(uint4*)&Bs_h[arow][kseg] = ph;
            *(uint4*)&Bs_l[arow][kseg] = pl;
            uint4 ph2, pl2;
            ph2.x = bh[8] | ((unsigned)bh[9] << 16);
            ph2.y = bh[10] | ((unsigned)bh[11] << 16);
            ph2.z = bh[12] | ((unsigned)bh[13] << 16);
            ph2.w = bh[14] | ((unsigned)bh[15] << 16);
            pl2.x = bl[8] | ((unsigned)bl[9] << 16);
            pl2.y = bl[10] | ((unsigned)bl[11] << 16);
            pl2.z = bl[12] | ((unsigned)bl[13] << 16);
            pl2.w = bl[14] | ((unsigned)bl[15] << 16);
            *(uint4*)&Bs_h[arow][kseg + 8] = ph2;
            *(uint4*)&Bs_l[arow][kseg + 8] = pl2;
        }
        __syncthreads();
        short8 ah[4], al[4], bh8[4], bl8[4];
#pragma unroll
        for (int i = 0; i < 4; ++i) {
            ah[i] = *(const short8*)&As_h[mb + i * 16 + row][grp8];
            al[i] = *(const short8*)&As_l[mb + i * 16 + row][grp8];
            bh8[i] = *(const short8*)&Bs_h[nb + i * 16 + row][grp8];
            bl8[i] = *(const short8*)&Bs_l[nb + i * 16 + row][grp8];
        }
#pragma unroll
        for (int i = 0; i < 4; ++i)
#pragma unroll
            for (int j = 0; j < 4; ++j) {
                acc[i][j] = __builtin_amdgcn_mfma_f32_16x16x32_bf16(ah[i], bh8[j], acc[i][j], 0, 0, 0);
                acc[i][j] = __builtin_amdgcn_mfma_f32_16x16x32_bf16(al[i], bh8[j], acc[i][j], 0, 0, 0);
                acc[i][j] = __builtin_amdgcn_mfma_f32_16x16x32_bf16(ah[i], bl8[j], acc[i][j], 0, 0, 0);
            }
        __syncthreads();
    }

    const int grp = lane >> 4;
#pragma unroll
    for (int i = 0; i < 4; ++i) {
        int mbase = m0 + mb + i * 16 + grp * 4;
#pragma unroll
        for (int j = 0; j < 4; ++j) {
            int n = n0 + nb + j * 16 + (lane & 15);
#pragma unroll
            for (int r = 0; r < 4; ++r) {
                float vv = acc[i][j][r];
                int mm = mbase + r;
                if (MODE == 4) {
                    if (n < N)
                        outDst[((size_t)(mm & 31) * Ss + (mm >> 5)) * Vv + n] = vv + bias1[n];
                } else {
                    Cmat[(size_t)mm * N + n] = vv + bias1[n] + bias2[n];
                }
            }
        }
    }
}

// ---------------------------------------------------------------------------
// Persistent LSTM chunk, 64 steps, hand-rolled flag barrier (no cg::sync).
// Grid 256 blocks x 512 threads (co-resident via cooperative launch).
// Barrier: per-block release flag -> block0 aggregates -> go token; readers
// spin with relaxed agent loads.  h is staged with agent-scope (L2-bypass)
// 8B atomic loads, so NO L2 invalidate is needed and the Wh slice / Gc stay
// L2-hot across all 64 steps.
// ---------------------------------------------------------------------------
__global__ __launch_bounds__(512) void lstm_chunk(
    const float* __restrict__ Gc,     // [64][32][4096] gate pre-activations
    const float* __restrict__ Wh,     // [4096][1024]
    const float* __restrict__ maskC,  // [64][32] this chunk's mask
    float* __restrict__ hb,           // [2][32][1024] (buffer 0 current at entry)
    float* __restrict__ cb,           // [32][1024]
    float* __restrict__ xout,         // [64][32][1024] this chunk's x slice
    unsigned* __restrict__ flags,     // [256] arrival slots (init 0)
    unsigned* __restrict__ go,        // [1] release token  (init 0)
    unsigned tokBase)                 // global chunk index * 64
{
    __shared__ float hs[2][32 * 132];   // double-buffered h chunk (33.8 KB)
    __shared__ float gbuf[8 * 16 * 32]; // k-eighth partials (16 KB)
    __shared__ float msk[64 * 32];      // this chunk's mask (8 KB)

    const int t   = threadIdx.x;
    const int bid = blockIdx.x;
    const int j0  = bid * 4;
    const int b   = t & 31;
    const int rg  = (t >> 5) & 1;   // 2 row-groups of 8 rows
    const int kh  = t >> 6;         // 8 k-sixteenth slots (16 floats per kc)

    for (int i = t; i < 64 * 32; i += 512) msk[i] = maskC[i];

    const int b2 = t & 31, d2 = (t >> 5) & 3;
    float c_reg = 0.f, h_reg = 0.f;
    if (t < 128) {
        c_reg = cb[b2 * Hh + j0 + d2];
        h_reg = hb[b2 * Hh + j0 + d2];   // buffer 0 current at chunk start
    }

    // 8 weight-row base pointers (local rows rg*8 .. rg*8+7), offset kh*16
    const float* wr[8];
#pragma unroll
    for (int ri = 0; ri < 8; ++ri) {
        int lr = rg * 8 + ri;                         // lr = q*4 + d
        wr[ri] = Wh + (size_t)((lr >> 2) * Hh + j0 + (lr & 3)) * Hh + kh * 16;
    }

    for (int s = 0; s < 64; ++s) {
        const float* hprev = hb + (s & 1) * 32768;
        float* hnext       = hb + ((s + 1) & 1) * 32768;
        const unsigned long long* hp64 = (const unsigned long long*)hprev;

        // prefetch this step's gate pre-activations (independent of h)
        float gq[4];
        if (t < 128) {
#pragma unroll
            for (int q = 0; q < 4; ++q)
                gq[q] = Gc[(size_t)s * (32 * FH) + b2 * FH + q * Hh + j0 + d2];
        }

        float ax[8], ay[8], az[8], aw[8];
#pragma unroll
        for (int ri = 0; ri < 8; ++ri) { ax[ri] = ay[ri] = az[ri] = aw[ri] = 0.f; }

        // ---- double-buffered staging: agent-scope (L2-bypass) 8B loads ----
        unsigned long long rr[4];
#pragma unroll
        for (int q = 0; q < 4; ++q) {
            int id = t * 4 + q;
            rr[q] = __hip_atomic_load(hp64 + (id >> 6) * 512 + (id & 63),
                                      __ATOMIC_RELAXED, __HIP_MEMORY_SCOPE_AGENT);
        }
        for (int kc = 0; kc < 8; ++kc) {
            __syncthreads();   // prior compute done with buf[kc&1]
#pragma unroll
            for (int q = 0; q < 4; ++q) {
                int id = t * 4 + q;
                *(unsigned long long*)&hs[kc & 1][(id >> 6) * 132 + (id & 63) * 2] = rr[q];
            }
            if (kc < 7) {
#pragma unroll
                for (int q = 0; q < 4; ++q) {
                    int id = t * 4 + q;
                    rr[q] = __hip_atomic_load(
                        hp64 + (id >> 6) * 512 + (kc + 1) * 64 + (id & 63),
                        __ATOMIC_RELAXED, __HIP_MEMORY_SCOPE_AGENT);
                }
            }
            __syncthreads();   // buf[kc&1] ready
            const float* hp = hs[kc & 1] + b * 132 + kh * 16;
#pragma unroll
            for (int u = 0; u < 4; ++u) {
                float4 hv = *(const float4*)(hp + u * 4);
#pragma unroll
                for (int ri = 0; ri < 8; ++ri) {
                    float4 wv = *(const float4*)(wr[ri] + kc * 128 + u * 4);
                    ax[ri] = fmaf(wv.x, hv.x, ax[ri]);
                    ay[ri] = fmaf(wv.y, hv.y, ay[ri]);
                    az[ri] = fmaf(wv.z, hv.z, az[ri]);
                    aw[ri] = fmaf(wv.w, hv.w, aw[ri]);
                }
            }
        }
        __syncthreads();
        // deposit k-eighth partials
#pragma unroll
        for (int ri = 0; ri < 8; ++ri) {
            int lr = rg * 8 + ri;
            gbuf[kh * 512 + lr * 32 + b] = (ax[ri] + ay[ri]) + (az[ri] + aw[ri]);
        }
        __syncthreads();
        if (t < 128) {
            float g4[4];
#pragma unroll
            for (int q = 0; q < 4; ++q) {
                int lr = q * 4 + d2;
                float sum = gq[q];
#pragma unroll
                for (int k2 = 0; k2 < 8; ++k2) sum += gbuf[k2 * 512 + lr * 32 + b2];
                g4[q] = sum;
            }
            float m  = msk[s * 32 + b2];
            float ct = sigf(g4[1]) * c_reg + sigf(g4[0]) * tanhf(g4[2]);
            float ht = sigf(g4[3]) * tanhf(ct);
            c_reg = ct + (c_reg - ct) * m;   // RHS c_reg is old c
            h_reg = ht + (h_reg - ht) * m;   // RHS h_reg is old h
            int j = j0 + d2;
            hnext[b2 * Hh + j] = h_reg;
            xout[(size_t)s * 32768 + b2 * Hh + j] = h_reg;
        }

        // ---- flag barrier (skip after last step; kernel end syncs) ----
        if (s < 63) {
            unsigned tok = tokBase + (unsigned)s + 1u;
            __syncthreads();   // drains all waves' stores to L2 (vmcnt)
            if (t == 0)        // RELEASE/agent: writebacks L2 then publishes
                __hip_atomic_store(&flags[bid], tok, __ATOMIC_RELEASE,
                                   __HIP_MEMORY_SCOPE_AGENT);
            if (bid == 0) {
                if (t < 256) {
                    while (__hip_atomic_load(&flags[t], __ATOMIC_RELAXED,
                                             __HIP_MEMORY_SCOPE_AGENT) < tok)
                        __builtin_amdgcn_s_sleep(1);
                }
                __syncthreads();
                if (t == 0)
                    __hip_atomic_store(go, tok, __ATOMIC_RELAXED,
                                       __HIP_MEMORY_SCOPE_AGENT);
            }
            if (t == 0) {
                while (__hip_atomic_load(go, __ATOMIC_RELAXED,
                                         __HIP_MEMORY_SCOPE_AGENT) < tok)
                    __builtin_amdgcn_s_sleep(1);
            }
            __syncthreads();
        }
    }
    if (t < 128) cb[b2 * Hh + j0 + d2] = c_reg;
}

__global__ __launch_bounds__(256) void init_hc(
    const float* __restrict__ h0, const float* __restrict__ c0,
    float* __restrict__ hb0, float* __restrict__ cb)
{
    int i = blockIdx.x * 256 + threadIdx.x;
    hb0[i] = h0[i];
    cb[i] = c0[i];
}

// ---------------------------------------------------------------------------
extern "C" void kernel_launch(void* const* d_in, const int* in_sizes, int n_in,
                              void* d_out, int out_size, void* d_ws, size_t ws_size,
                              hipStream_t stream)
{
    const int*   src      = (const int*)  d_in[0];
    const float* fix_pred = (const float*)d_in[1];
    const float* emb      = (const float*)d_in[2];
    const float* W_lin    = (const float*)d_in[3];
    const float* b_lin    = (const float*)d_in[4];
    const float* W_ih     = (const float*)d_in[5];
    const float* W_hh     = (const float*)d_in[6];
    const float* b_ih     = (const float*)d_in[7];
    const float* b_hh     = (const float*)d_in[8];
    const float* fc_W1    = (const float*)d_in[9];
    const float* fc_b1    = (const float*)d_in[10];
    const float* fc_W2    = (const float*)d_in[11];
    const float* fc_b2    = (const float*)d_in[12];
    const float* h0       = (const float*)d_in[13];
    const float* c0       = (const float*)d_in[14];
    float* out = (float*)d_out;

    // workspace layout (floats)
    float* ws    = (float*)d_ws;
    float* ix    = ws;                    // 8388608  input_x [S*B][H]
    float* xbuf  = ix + 8388608;          // 8388608  x       [S*B][H]
    float* Gch   = xbuf + 8388608;        // 8388608  G chunk [2048][4096]
    float* hid   = Gch;                   // alias: hid [8192][512]
    unsigned* wpack = (unsigned*)(Gch + 8388608);  // 4194304 u32: Wi[l] packed
    float* hb    = (float*)(wpack + 4194304);      // 65536 (double-buffered h)
    float* cb    = hb + 65536;            // 32768
    float* mask  = cb + 32768;            // 24576
    float* gate  = mask + 24576;          // 24576
    unsigned* flags = (unsigned*)(gate + 24576);   // 256 arrival + 1 go
    unsigned* go    = flags + 256;

    // reset barrier tokens (graph-replay idempotency)
    hipMemsetAsync(flags, 0, 257 * sizeof(unsigned), stream);

    maskgate_kernel<<<32, 256, 0, stream>>>(fix_pred, mask, gate);

    // input_x = emb[src] @ W_lin^T + b_lin : M=8192 N=1024 K=512 (fp32)
    gemm_nt<0><<<dim3(16, 128), 256, 0, stream>>>(
        nullptr, W_lin, b_lin, ix, 8192, 1024, 512, src, emb);

    for (int l = 0; l < Ll; ++l) {
        pack_split<<<4096, 256, 0, stream>>>(W_ih + (size_t)l * FH * Hh, wpack, 1048576);
        init_hc<<<128, 256, 0, stream>>>(h0 + (size_t)l * 32768, c0 + (size_t)l * 32768, hb, cb);
        const float* Wh = W_hh + (size_t)l * FH * Hh;
        const float* bi = b_ih + (size_t)l * FH;
        const float* bh = b_hh + (size_t)l * FH;
        for (int ch = 0; ch < 4; ++ch) {
            int rowOff = ch * 2048;
            // G = inp_seq @ Wi^T + bi + bh : M=2048 N=4096 K=1024 (MFMA split-3)
            if (l == 0) {
                gemm_mfma<1><<<dim3(32, 16), 256, 0, stream>>>(
                    nullptr, wpack, bi, bh, Gch, 2048, 4096, 1024,
                    nullptr, ix, gate + l * 8192, rowOff, nullptr);
            } else {
                gemm_mfma<2><<<dim3(32, 16), 256, 0, stream>>>(
                    nullptr, wpack, bi, bh, Gch, 2048, 4096, 1024,
                    xbuf, ix, gate + l * 8192, rowOff, nullptr);
            }
            // 64 LSTM steps in one cooperative launch (flag barrier inside)
            {
                const float* GcArg   = Gch;
                const float* WhArg   = Wh;
                const float* maskArg = mask + l * 8192 + ch * 64 * 32;
                float* hbArg = hb;
                float* cbArg = cb;
                float* xoArg = xbuf + (size_t)ch * 64 * 32768;
                unsigned* flArg = flags;
                unsigned* goArg = go;
                unsigned tokBase = (unsigned)((l * 4 + ch) * 64);
                void* args[] = {
                    (void*)&GcArg, (void*)&WhArg, (void*)&maskArg,
                    (void*)&hbArg, (void*)&cbArg, (void*)&xoArg,
                    (void*)&flArg, (void*)&goArg, (void*)&tokBase
                };
                hipLaunchCooperativeKernel((const void*)lstm_chunk,
                                           dim3(256), dim3(512), args, 0, stream);
            }
        }
    }

    // hid = tanh(x @ fc_W1^T + fc_b1) : M=8192 N=512 K=1024 (fp32)
    gemm_nt<3><<<dim3(8, 128), 256, 0, stream>>>(
        xbuf, fc_W1, fc_b1, hid, 8192, 512, 1024, nullptr, nullptr);

    // pack fc_W2 into the now-dead ix buffer; out = hid @ fc_W2^T + fc_b2
    unsigned* w2pack = (unsigned*)ix;
    pack_split<<<5000, 256, 0, stream>>>(fc_W2, w2pack, 1280000);
    gemm_mfma<4><<<dim3(79, 64), 256, 0, stream>>>(
        hid, w2pack, fc_b2, nullptr, nullptr, 8192, 10000, 512,
        nullptr, nullptr, nullptr, 0, out);
}

// Round 3
// 21245.975 us; speedup vs baseline: 2.7512x; 1.4946x over previous
//
#include <hip/hip_runtime.h>
#include <hip/hip_cooperative_groups.h>
#include <math.h>

#define Bb 32
#define Ss 256
#define Vv 10000
#define Ee 512
#define Hh 1024
#define Ll 3
#define FH 4096

typedef short short8 __attribute__((ext_vector_type(8)));
typedef float floatx4 __attribute__((ext_vector_type(4)));

__device__ __forceinline__ float sigf(float x) { return 1.0f / (1.0f + expf(-x)); }

// 16B agent-scope (L2-bypass, IF-served) load/store via sc1 flag.
// Untracked by compiler -> explicit s_waitcnt vmcnt(0) before use / release.
#define HLOAD16(dst, ptr) \
    asm volatile("global_load_dwordx4 %0, %1, off sc1" : "=v"(dst) : "v"(ptr) : "memory")
#define HSTORE16(ptr, val) \
    asm volatile("global_store_dwordx4 %0, %1, off sc1" :: "v"(ptr), "v"(val) : "memory")
#define WAIT_VM0() do { asm volatile("s_waitcnt vmcnt(0)" ::: "memory"); \
                        __builtin_amdgcn_sched_barrier(0); } while (0)

// split fp32 -> bf16 hi/lo (RNE). packed u32: low16 = hi, high16 = lo
__device__ __forceinline__ unsigned pack_hl(float x) {
    unsigned u = __float_as_uint(x);
    unsigned r = u + 0x7fff + ((u >> 16) & 1);
    unsigned hi = r >> 16;
    float hf = __uint_as_float(hi << 16);
    float l = x - hf;
    unsigned ul = __float_as_uint(l);
    unsigned rl = ul + 0x7fff + ((ul >> 16) & 1);
    return hi | ((rl >> 16) << 16);
}
__device__ __forceinline__ void split_hl(float x, unsigned short& h, unsigned short& l) {
    unsigned p = pack_hl(x);
    h = (unsigned short)(p & 0xffff);
    l = (unsigned short)(p >> 16);
}

// ---------------------------------------------------------------------------
// pack fp32 weights -> packed bf16 hi/lo u32 (vectorized float4)
// ---------------------------------------------------------------------------
__global__ __launch_bounds__(256) void pack_split(
    const float* __restrict__ src, unsigned* __restrict__ dst, int n4)
{
    int i = blockIdx.x * 256 + threadIdx.x;
    if (i < n4) {
        float4 v = ((const float4*)src)[i];
        uint4 o;
        o.x = pack_hl(v.x); o.y = pack_hl(v.y); o.z = pack_hl(v.z); o.w = pack_hl(v.w);
        ((uint4*)dst)[i] = o;
    }
}

// ---------------------------------------------------------------------------
// K1: layer-norm over seq dim of fix_pred, then per-layer mask/gate scalars.
// mask/gate layout: [L][S][B] -> idx l*8192 + s*32 + b
// ---------------------------------------------------------------------------
__global__ __launch_bounds__(256) void maskgate_kernel(
    const float* __restrict__ fp_in, float* __restrict__ mask, float* __restrict__ gate)
{
    __shared__ float red[256];
    int b = blockIdx.x, t = threadIdx.x;
    float v = fp_in[b * Ss + t];
    red[t] = v;
    __syncthreads();
    for (int o = 128; o > 0; o >>= 1) { if (t < o) red[t] += red[t + o]; __syncthreads(); }
    float mu = red[0] * (1.0f / Ss);
    __syncthreads();
    float d = v - mu;
    red[t] = d * d;
    __syncthreads();
    for (int o = 128; o > 0; o >>= 1) { if (t < o) red[t] += red[t + o]; __syncthreads(); }
    float var = red[0] * (1.0f / Ss);
    float fp = d * (1.0f / sqrtf(var + 1e-5f));
    fp = (fp + 1.96f) / 3.92f * 12.0f;
    float alpha0 = (11.0f - fp) * 0.25f;   // RESCALE = 12//3 = 4
    for (int l = 0; l < Ll; ++l) {
        float a = alpha0 - (float)l;
        float m = sigf(a);
        float g = sigf(a + 1.0f) - m;
        mask[l * (Ss * Bb) + t * Bb + b] = m;
        gate[l * (Ss * Bb) + t * Bb + b] = g;
    }
}

// ---------------------------------------------------------------------------
// fp32 NT GEMM (kept for the two small GEMMs):
// MODE 0: A gathered from emb via src; C = input_x + b_lin
// MODE 3: A plain; C = tanh(acc + bias)   (FC1 -> hid)
// ---------------------------------------------------------------------------
template <int MODE>
__global__ __launch_bounds__(256) void gemm_nt(
    const float* __restrict__ Amat, const float* __restrict__ Bmat,
    const float* __restrict__ bias1,
    float* __restrict__ Cmat, int M, int N, int K,
    const int* __restrict__ srcIdx, const float* __restrict__ embTab)
{
    __shared__ float As[16][68];
    __shared__ float Bs[16][68];
    int t = threadIdx.x;
    int tx = t & 15, ty = t >> 4;
    int n0 = blockIdx.x * 64, m0 = blockIdx.y * 64;
    int li = t >> 2;
    int lk = (t & 3) * 4;
    float acc[4][4];
#pragma unroll
    for (int y = 0; y < 4; ++y)
#pragma unroll
        for (int x = 0; x < 4; ++x) acc[y][x] = 0.0f;

    for (int k0 = 0; k0 < K; k0 += 16) {
        float a0, a1, a2, a3;
        {
            int r = m0 + li;
            if (MODE == 0) {
                int idx = srcIdx[(r & 31) * Ss + (r >> 5)];
                float4 v = *(const float4*)(embTab + (size_t)idx * K + (k0 + lk));
                a0 = v.x; a1 = v.y; a2 = v.z; a3 = v.w;
            } else {
                float4 v = *(const float4*)(Amat + (size_t)r * K + (k0 + lk));
                a0 = v.x; a1 = v.y; a2 = v.z; a3 = v.w;
            }
        }
        As[lk + 0][li] = a0; As[lk + 1][li] = a1; As[lk + 2][li] = a2; As[lk + 3][li] = a3;
        {
            int n = n0 + li;
            float b0 = 0.f, b1 = 0.f, b2 = 0.f, b3 = 0.f;
            if (n < N) {
                float4 v = *(const float4*)(Bmat + (size_t)n * K + (k0 + lk));
                b0 = v.x; b1 = v.y; b2 = v.z; b3 = v.w;
            }
            Bs[lk + 0][li] = b0; Bs[lk + 1][li] = b1; Bs[lk + 2][li] = b2; Bs[lk + 3][li] = b3;
        }
        __syncthreads();
#pragma unroll
        for (int kk = 0; kk < 16; ++kk) {
            float4 av = *(const float4*)&As[kk][ty * 4];
            float4 bv = *(const float4*)&Bs[kk][tx * 4];
            float avc[4] = {av.x, av.y, av.z, av.w};
            float bvc[4] = {bv.x, bv.y, bv.z, bv.w};
#pragma unroll
            for (int y = 0; y < 4; ++y)
#pragma unroll
                for (int x = 0; x < 4; ++x)
                    acc[y][x] = fmaf(avc[y], bvc[x], acc[y][x]);
        }
        __syncthreads();
    }
#pragma unroll
    for (int y = 0; y < 4; ++y) {
        int r = m0 + ty * 4 + y;
#pragma unroll
        for (int x = 0; x < 4; ++x) {
            int n = n0 + tx * 4 + x;
            if (n < N) {
                float vv = acc[y][x];
                if (MODE == 0) Cmat[(size_t)r * N + n] = vv + bias1[n];
                else           Cmat[(size_t)r * N + n] = tanhf(vv + bias1[n]);
            }
        }
    }
}

// ---------------------------------------------------------------------------
// MFMA split-bf16 NT GEMM: C[M,N] = A[M,K] * B[N,K]^T in ~fp32 precision.
// ---------------------------------------------------------------------------
template <int MODE>
__global__ __launch_bounds__(256) void gemm_mfma(
    const float* __restrict__ Amat, const unsigned* __restrict__ Bp,
    const float* __restrict__ bias1, const float* __restrict__ bias2,
    float* __restrict__ Cmat, int M, int N, int K,
    const float* __restrict__ xb, const float* __restrict__ ixb,
    const float* __restrict__ gateArr, int rowOff,
    float* __restrict__ outDst)
{
    __shared__ unsigned short As_h[128][40];
    __shared__ unsigned short As_l[128][40];
    __shared__ unsigned short Bs_h[128][40];
    __shared__ unsigned short Bs_l[128][40];

    const int t = threadIdx.x;
    const int n0 = blockIdx.x * 128, m0 = blockIdx.y * 128;
    const int lane = t & 63, w = t >> 6;
    const int mb = (w & 1) * 64, nb = (w >> 1) * 64;
    const int row = lane & 15, grp8 = (lane >> 4) * 8;

    const int arow = t >> 1;
    const int kseg = (t & 1) * 16;

    float gblend = 0.0f;
    const float* aptr = nullptr;
    const float* xptr = nullptr;
    if (MODE == 1 || MODE == 2) {
        int rg = rowOff + m0 + arow;
        gblend = gateArr[rg];
        aptr = ixb + (size_t)rg * K;
        if (MODE == 2) xptr = xb + (size_t)rg * K;
    } else {
        aptr = Amat + (size_t)(m0 + arow) * K;
    }
    const int bn = n0 + arow;
    const unsigned* bptr = Bp + (size_t)(bn < N ? bn : 0) * K;
    const bool bvalid = (bn < N);

    floatx4 acc[4][4];
#pragma unroll
    for (int i = 0; i < 4; ++i)
#pragma unroll
        for (int j = 0; j < 4; ++j)
            acc[i][j] = (floatx4){0.f, 0.f, 0.f, 0.f};

    for (int k0 = 0; k0 < K; k0 += 32) {
        unsigned short hbuf[16], lbuf[16];
#pragma unroll
        for (int u = 0; u < 4; ++u) {
            float4 vi = *(const float4*)(aptr + k0 + kseg + u * 4);
            float vals[4] = {vi.x, vi.y, vi.z, vi.w};
            if (MODE == 1) {
#pragma unroll
                for (int c = 0; c < 4; ++c) vals[c] *= gblend;
            } else if (MODE == 2) {
                float4 vx = *(const float4*)(xptr + k0 + kseg + u * 4);
                float xs[4] = {vx.x, vx.y, vx.z, vx.w};
#pragma unroll
                for (int c = 0; c < 4; ++c) vals[c] = xs[c] + (vals[c] - xs[c]) * gblend;
            }
#pragma unroll
            for (int c = 0; c < 4; ++c) split_hl(vals[c], hbuf[u * 4 + c], lbuf[u * 4 + c]);
        }
        {
            uint4 ph, pl;
            ph.x = hbuf[0] | ((unsigned)hbuf[1] << 16);
            ph.y = hbuf[2] | ((unsigned)hbuf[3] << 16);
            ph.z = hbuf[4] | ((unsigned)hbuf[5] << 16);
            ph.w = hbuf[6] | ((unsigned)hbuf[7] << 16);
            pl.x = lbuf[0] | ((unsigned)lbuf[1] << 16);
            pl.y = lbuf[2] | ((unsigned)lbuf[3] << 16);
            pl.z = lbuf[4] | ((unsigned)lbuf[5] << 16);
            pl.w = lbuf[6] | ((unsigned)lbuf[7] << 16);
            *(uint4*)&As_h[arow][kseg] = ph;
            *(uint4*)&As_l[arow][kseg] = pl;
            uint4 ph2, pl2;
            ph2.x = hbuf[8] | ((unsigned)hbuf[9] << 16);
            ph2.y = hbuf[10] | ((unsigned)hbuf[11] << 16);
            ph2.z = hbuf[12] | ((unsigned)hbuf[13] << 16);
            ph2.w = hbuf[14] | ((unsigned)hbuf[15] << 16);
            pl2.x = lbuf[8] | ((unsigned)lbuf[9] << 16);
            pl2.y = lbuf[10] | ((unsigned)lbuf[11] << 16);
            pl2.z = lbuf[12] | ((unsigned)lbuf[13] << 16);
            pl2.w = lbuf[14] | ((unsigned)lbuf[15] << 16);
            *(uint4*)&As_h[arow][kseg + 8] = ph2;
            *(uint4*)&As_l[arow][kseg + 8] = pl2;
        }
        {
            unsigned short bh[16], bl[16];
            if (bvalid) {
#pragma unroll
                for (int u = 0; u < 4; ++u) {
                    uint4 q = *(const uint4*)(bptr + k0 + kseg + u * 4);
                    unsigned qs[4] = {q.x, q.y, q.z, q.w};
#pragma unroll
                    for (int c = 0; c < 4; ++c) {
                        bh[u * 4 + c] = (unsigned short)(qs[c] & 0xffff);
                        bl[u * 4 + c] = (unsigned short)(qs[c] >> 16);
                    }
                }
            } else {
#pragma unroll
                for (int c = 0; c < 16; ++c) { bh[c] = 0; bl[c] = 0; }
            }
            uint4 ph, pl;
            ph.x = bh[0] | ((unsigned)bh[1] << 16);
            ph.y = bh[2] | ((unsigned)bh[3] << 16);
            ph.z = bh[4] | ((unsigned)bh[5] << 16);
            ph.w = bh[6] | ((unsigned)bh[7] << 16);
            pl.x = bl[0] | ((unsigned)bl[1] << 16);
            pl.y = bl[2] | ((unsigned)bl[3] << 16);
            pl.z = bl[4] | ((unsigned)bl[5] << 16);
            pl.w = bl[6] | ((unsigned)bl[7] << 16);
            *(uint4*)&Bs_h[arow][kseg] = ph;
            *(uint4*)&Bs_l[arow][kseg] = pl;
            uint4 ph2, pl2;
            ph2.x = bh[8] | ((unsigned)bh[9] << 16);
            ph2.y = bh[10] | ((unsigned)bh[11] << 16);
            ph2.z = bh[12] | ((unsigned)bh[13] << 16);
            ph2.w = bh[14] | ((unsigned)bh[15] << 16);
            pl2.x = bl[8] | ((unsigned)bl[9] << 16);
            pl2.y = bl[10] | ((unsigned)bl[11] << 16);
            pl2.z = bl[12] | ((unsigned)bl[13] << 16);
            pl2.w = bl[14] | ((unsigned)bl[15] << 16);
            *(uint4*)&Bs_h[arow][kseg + 8] = ph2;
            *(uint4*)&Bs_l[arow][kseg + 8] = pl2;
        }
        __syncthreads();
        short8 ah[4], al[4], bh8[4], bl8[4];
#pragma unroll
        for (int i = 0; i < 4; ++i) {
            ah[i] = *(const short8*)&As_h[mb + i * 16 + row][grp8];
            al[i] = *(const short8*)&As_l[mb + i * 16 + row][grp8];
            bh8[i] = *(const short8*)&Bs_h[nb + i * 16 + row][grp8];
            bl8[i] = *(const short8*)&Bs_l[nb + i * 16 + row][grp8];
        }
#pragma unroll
        for (int i = 0; i < 4; ++i)
#pragma unroll
            for (int j = 0; j < 4; ++j) {
                acc[i][j] = __builtin_amdgcn_mfma_f32_16x16x32_bf16(ah[i], bh8[j], acc[i][j], 0, 0, 0);
                acc[i][j] = __builtin_amdgcn_mfma_f32_16x16x32_bf16(al[i], bh8[j], acc[i][j], 0, 0, 0);
                acc[i][j] = __builtin_amdgcn_mfma_f32_16x16x32_bf16(ah[i], bl8[j], acc[i][j], 0, 0, 0);
            }
        __syncthreads();
    }

    const int grp = lane >> 4;
#pragma unroll
    for (int i = 0; i < 4; ++i) {
        int mbase = m0 + mb + i * 16 + grp * 4;
#pragma unroll
        for (int j = 0; j < 4; ++j) {
            int n = n0 + nb + j * 16 + (lane & 15);
#pragma unroll
            for (int r = 0; r < 4; ++r) {
                float vv = acc[i][j][r];
                int mm = mbase + r;
                if (MODE == 4) {
                    if (n < N)
                        outDst[((size_t)(mm & 31) * Ss + (mm >> 5)) * Vv + n] = vv + bias1[n];
                } else {
                    Cmat[(size_t)mm * N + n] = vv + bias1[n] + bias2[n];
                }
            }
        }
    }
}

// ---------------------------------------------------------------------------
// Persistent LSTM chunk, 64 steps, flag barrier (round-2 protocol, proven).
// NEW: h is REPLICATED into 8 copies per parity. Writers publish h via sc1
// (write-through to IF) float4 stores to all 8 copies; block bid reads copy
// bid&7 with 16B sc1 loads -> the 256-block redundant read spreads over 8x
// the IF slices. LDS staging stores are two contiguous float4/thread
// (4-way structural max, no 8-way conflicts).
// ---------------------------------------------------------------------------
__global__ __launch_bounds__(512) void lstm_chunk(
    const float* __restrict__ Gc,     // [64][32][4096] gate pre-activations
    const float* __restrict__ Wh,     // [4096][1024]
    const float* __restrict__ maskC,  // [64][32] this chunk's mask
    float* __restrict__ hc,           // [2][8][32][1024] h copies (parity,copy)
    float* __restrict__ cb,           // [32][1024]
    float* __restrict__ xout,         // [64][32][1024] this chunk's x slice
    unsigned* __restrict__ flags,     // [256] arrival slots (init 0)
    unsigned* __restrict__ go,        // [1] release token  (init 0)
    unsigned tokBase)                 // global chunk index * 64
{
    __shared__ float hs[2][32 * 132];   // double-buffered h chunk (33.8 KB)
    __shared__ float gbuf[8 * 16 * 32]; // k-eighth partials (16 KB)
    __shared__ float msk[64 * 32];      // this chunk's mask (8 KB)
    __shared__ float hstage[128];       // per-step h gather for fat stores

    const int t    = threadIdx.x;
    const int bid  = blockIdx.x;
    const int j0   = bid * 4;
    const int b    = t & 31;
    const int rg   = (t >> 5) & 1;   // 2 row-groups of 8 rows
    const int kh   = t >> 6;         // 8 k-eighths (16 floats per kc)
    const int copy = bid & 7;

    for (int i = t; i < 64 * 32; i += 512) msk[i] = maskC[i];

    const int b2 = t & 31, d2 = (t >> 5) & 3;
    float c_reg = 0.f, h_reg = 0.f;
    if (t < 128) {
        c_reg = cb[b2 * Hh + j0 + d2];
        // parity 0, own copy; fresh via kernel-boundary coherence
        h_reg = hc[copy * 32768 + b2 * Hh + j0 + d2];
    }

    // 8 weight-row base pointers (local rows rg*8 .. rg*8+7), offset kh*16
    const float* wr[8];
#pragma unroll
    for (int ri = 0; ri < 8; ++ri) {
        int lr = rg * 8 + ri;                         // lr = q*4 + d
        wr[ri] = Wh + (size_t)((lr >> 2) * Hh + j0 + (lr & 3)) * Hh + kh * 16;
    }

    // staging geometry: thread t stages float4 at (batch sb0, offset sk4)
    // and (batch sb0+16, offset sk4) -> lane-consecutive 16B, coalesced.
    const int sb0 = t >> 5;            // 0..15
    const int sk4 = (t & 31) * 4;      // 0..124

    for (int s = 0; s < 64; ++s) {
        const float* hprev = hc + (s & 1) * (8 * 32768) + copy * 32768;

        // prefetch this step's gate pre-activations (independent of h)
        float gq[4];
        if (t < 128) {
#pragma unroll
            for (int q = 0; q < 4; ++q)
                gq[q] = Gc[(size_t)s * (32 * FH) + b2 * FH + q * Hh + j0 + d2];
        }

        float ax[8], ay[8], az[8], aw[8];
#pragma unroll
        for (int ri = 0; ri < 8; ++ri) { ax[ri] = ay[ri] = az[ri] = aw[ri] = 0.f; }

        // ---- double-buffered staging: 16B sc1 (L2-bypass) loads ----
        floatx4 r0, r1;
        HLOAD16(r0, hprev + sb0 * Hh + sk4);
        HLOAD16(r1, hprev + (sb0 + 16) * Hh + sk4);

        for (int kc = 0; kc < 8; ++kc) {
            __syncthreads();   // prior compute done with buf[kc&1]
            WAIT_VM0();        // r0,r1 arrived (hw vmcnt covers asm loads)
            *(floatx4*)&hs[kc & 1][sb0 * 132 + sk4] = r0;
            *(floatx4*)&hs[kc & 1][(sb0 + 16) * 132 + sk4] = r1;
            if (kc < 7) {
                HLOAD16(r0, hprev + sb0 * Hh + (kc + 1) * 128 + sk4);
                HLOAD16(r1, hprev + (sb0 + 16) * Hh + (kc + 1) * 128 + sk4);
            }
            __syncthreads();   // buf[kc&1] ready
            const float* hp = hs[kc & 1] + b * 132 + kh * 16;
#pragma unroll
            for (int u = 0; u < 4; ++u) {
                float4 hv = *(const float4*)(hp + u * 4);
#pragma unroll
                for (int ri = 0; ri < 8; ++ri) {
                    float4 wv = *(const float4*)(wr[ri] + kc * 128 + u * 4);
                    ax[ri] = fmaf(wv.x, hv.x, ax[ri]);
                    ay[ri] = fmaf(wv.y, hv.y, ay[ri]);
                    az[ri] = fmaf(wv.z, hv.z, az[ri]);
                    aw[ri] = fmaf(wv.w, hv.w, aw[ri]);
                }
            }
        }
        __syncthreads();
        // deposit k-eighth partials
#pragma unroll
        for (int ri = 0; ri < 8; ++ri) {
            int lr = rg * 8 + ri;
            gbuf[kh * 512 + lr * 32 + b] = (ax[ri] + ay[ri]) + (az[ri] + aw[ri]);
        }
        __syncthreads();
        if (t < 128) {
            float g4[4];
#pragma unroll
            for (int q = 0; q < 4; ++q) {
                int lr = q * 4 + d2;
                float sum = gq[q];
#pragma unroll
                for (int k2 = 0; k2 < 8; ++k2) sum += gbuf[k2 * 512 + lr * 32 + b2];
                g4[q] = sum;
            }
            float m  = msk[s * 32 + b2];
            float ct = sigf(g4[1]) * c_reg + sigf(g4[0]) * tanhf(g4[2]);
            float ht = sigf(g4[3]) * tanhf(ct);
            c_reg = ct + (c_reg - ct) * m;   // RHS c_reg is old c
            h_reg = ht + (h_reg - ht) * m;   // RHS h_reg is old h
            hstage[b2 * 4 + d2] = h_reg;
            xout[(size_t)s * 32768 + b2 * Hh + j0 + d2] = h_reg;
        }
        __syncthreads();
        // fat publication: 32 threads store float4 to all 8 copies (sc1)
        if (t < 32) {
            floatx4 hv = *(floatx4*)&hstage[t * 4];
            float* nbase = hc + ((s + 1) & 1) * (8 * 32768) + t * Hh + j0;
#pragma unroll
            for (int c = 0; c < 8; ++c)
                HSTORE16(nbase + c * 32768, hv);
        }
        // drain asm stores (hw vmcnt) before the release becomes visible
        asm volatile("s_waitcnt vmcnt(0)" ::: "memory");

        // ---- flag barrier (skip after last step; kernel end syncs) ----
        if (s < 63) {
            unsigned tok = tokBase + (unsigned)s + 1u;
            __syncthreads();   // all waves drained (compiler emits waitcnt)
            if (t == 0)        // RELEASE/agent: publishes after L2 writeback
                __hip_atomic_store(&flags[bid], tok, __ATOMIC_RELEASE,
                                   __HIP_MEMORY_SCOPE_AGENT);
            if (bid == 0) {
                if (t < 256) {
                    while (__hip_atomic_load(&flags[t], __ATOMIC_RELAXED,
                                             __HIP_MEMORY_SCOPE_AGENT) < tok)
                        __builtin_amdgcn_s_sleep(1);
                }
                __syncthreads();
                if (t == 0)
                    __hip_atomic_store(go, tok, __ATOMIC_RELAXED,
                                       __HIP_MEMORY_SCOPE_AGENT);
            }
            if (t == 0) {
                while (__hip_atomic_load(go, __ATOMIC_RELAXED,
                                         __HIP_MEMORY_SCOPE_AGENT) < tok)
                    __builtin_amdgcn_s_sleep(1);
            }
            __syncthreads();
        }
    }
    if (t < 128) cb[b2 * Hh + j0 + d2] = c_reg;
}

__global__ __launch_bounds__(256) void init_hc(
    const float* __restrict__ h0, const float* __restrict__ c0,
    float* __restrict__ hc, float* __restrict__ cb)
{
    int i = blockIdx.x * 256 + threadIdx.x;   // 32768 total
    float h = h0[i];
#pragma unroll
    for (int c = 0; c < 8; ++c) hc[c * 32768 + i] = h;   // parity 0, 8 copies
    cb[i] = c0[i];
}

// ---------------------------------------------------------------------------
extern "C" void kernel_launch(void* const* d_in, const int* in_sizes, int n_in,
                              void* d_out, int out_size, void* d_ws, size_t ws_size,
                              hipStream_t stream)
{
    const int*   src      = (const int*)  d_in[0];
    const float* fix_pred = (const float*)d_in[1];
    const float* emb      = (const float*)d_in[2];
    const float* W_lin    = (const float*)d_in[3];
    const float* b_lin    = (const float*)d_in[4];
    const float* W_ih     = (const float*)d_in[5];
    const float* W_hh     = (const float*)d_in[6];
    const float* b_ih     = (const float*)d_in[7];
    const float* b_hh     = (const float*)d_in[8];
    const float* fc_W1    = (const float*)d_in[9];
    const float* fc_b1    = (const float*)d_in[10];
    const float* fc_W2    = (const float*)d_in[11];
    const float* fc_b2    = (const float*)d_in[12];
    const float* h0       = (const float*)d_in[13];
    const float* c0       = (const float*)d_in[14];
    float* out = (float*)d_out;

    // workspace layout (floats)
    float* ws    = (float*)d_ws;
    float* ix    = ws;                    // 8388608  input_x [S*B][H]
    float* xbuf  = ix + 8388608;          // 8388608  x       [S*B][H]
    float* Gch   = xbuf + 8388608;        // 8388608  G chunk [2048][4096]
    float* hid   = Gch;                   // alias: hid [8192][512]
    unsigned* wpack = (unsigned*)(Gch + 8388608);  // 4194304 u32: Wi[l] packed
    float* hc    = (float*)(wpack + 4194304);      // 524288: h copies [2][8][32768]
    float* cb    = hc + 524288;           // 32768
    float* mask  = cb + 32768;            // 24576
    float* gate  = mask + 24576;          // 24576
    unsigned* flags = (unsigned*)(gate + 24576);   // 256 arrival + 1 go
    unsigned* go    = flags + 256;
    // total ~= 30.0M floats ~= 120 MB

    // reset barrier tokens (graph-replay idempotency)
    hipMemsetAsync(flags, 0, 257 * sizeof(unsigned), stream);

    maskgate_kernel<<<32, 256, 0, stream>>>(fix_pred, mask, gate);

    // input_x = emb[src] @ W_lin^T + b_lin : M=8192 N=1024 K=512 (fp32)
    gemm_nt<0><<<dim3(16, 128), 256, 0, stream>>>(
        nullptr, W_lin, b_lin, ix, 8192, 1024, 512, src, emb);

    for (int l = 0; l < Ll; ++l) {
        pack_split<<<4096, 256, 0, stream>>>(W_ih + (size_t)l * FH * Hh, wpack, 1048576);
        init_hc<<<128, 256, 0, stream>>>(h0 + (size_t)l * 32768, c0 + (size_t)l * 32768, hc, cb);
        const float* Wh = W_hh + (size_t)l * FH * Hh;
        const float* bi = b_ih + (size_t)l * FH;
        const float* bh = b_hh + (size_t)l * FH;
        for (int ch = 0; ch < 4; ++ch) {
            int rowOff = ch * 2048;
            // G = inp_seq @ Wi^T + bi + bh : M=2048 N=4096 K=1024 (MFMA split-3)
            if (l == 0) {
                gemm_mfma<1><<<dim3(32, 16), 256, 0, stream>>>(
                    nullptr, wpack, bi, bh, Gch, 2048, 4096, 1024,
                    nullptr, ix, gate + l * 8192, rowOff, nullptr);
            } else {
                gemm_mfma<2><<<dim3(32, 16), 256, 0, stream>>>(
                    nullptr, wpack, bi, bh, Gch, 2048, 4096, 1024,
                    xbuf, ix, gate + l * 8192, rowOff, nullptr);
            }
            // 64 LSTM steps in one cooperative launch (flag barrier inside)
            {
                const float* GcArg   = Gch;
                const float* WhArg   = Wh;
                const float* maskArg = mask + l * 8192 + ch * 64 * 32;
                float* hcArg = hc;
                float* cbArg = cb;
                float* xoArg = xbuf + (size_t)ch * 64 * 32768;
                unsigned* flArg = flags;
                unsigned* goArg = go;
                unsigned tokBase = (unsigned)((l * 4 + ch) * 64);
                void* args[] = {
                    (void*)&GcArg, (void*)&WhArg, (void*)&maskArg,
                    (void*)&hcArg, (void*)&cbArg, (void*)&xoArg,
                    (void*)&flArg, (void*)&goArg, (void*)&tokBase
                };
                hipLaunchCooperativeKernel((const void*)lstm_chunk,
                                           dim3(256), dim3(512), args, 0, stream);
            }
        }
    }

    // hid = tanh(x @ fc_W1^T + fc_b1) : M=8192 N=512 K=1024 (fp32)
    gemm_nt<3><<<dim3(8, 128), 256, 0, stream>>>(
        xbuf, fc_W1, fc_b1, hid, 8192, 512, 1024, nullptr, nullptr);

    // pack fc_W2 into the now-dead ix buffer; out = hid @ fc_W2^T + fc_b2
    unsigned* w2pack = (unsigned*)ix;
    pack_split<<<5000, 256, 0, stream>>>(fc_W2, w2pack, 1280000);
    gemm_mfma<4><<<dim3(79, 64), 256, 0, stream>>>(
        hid, w2pack, fc_b2, nullptr, nullptr, 8192, 10000, 512,
        nullptr, nullptr, nullptr, 0, out);
}